// Round 2
// baseline (577.502 us; speedup 1.0000x reference)
//
#include <hip/hip_runtime.h>

typedef __attribute__((ext_vector_type(8))) short short8;
typedef __attribute__((ext_vector_type(4))) float f32x4;

__device__ inline unsigned short f2bf(float f) {
  union { float f; unsigned u; } v; v.f = f;
  unsigned r = v.u + 0x7fffu + ((v.u >> 16) & 1u);
  return (unsigned short)(r >> 16);
}
__device__ inline float bf2f(unsigned short b) {
  union { unsigned u; float f; } v; v.u = ((unsigned)b) << 16;
  return v.f;
}

// ---------------- edge dtype detection ----------------
// int64 values < 2^31 have all-zero high words at odd int32 indices.
__global__ void detect_k(const int* __restrict__ ei, int E, int* __restrict__ flag) {
  __shared__ int s;
  if (threadIdx.x == 0) s = 0;
  __syncthreads();
  int acc = 0;
  for (int i = threadIdx.x; i < 1024; i += 256) {
    int idx = 2 * i + 1;
    if (idx < 2 * E) acc |= ei[idx];
  }
  if (acc) atomicOr(&s, 1);
  __syncthreads();
  if (threadIdx.x == 0) *flag = (s == 0) ? 1 : 0;  // 1 = int64 layout
}

__device__ inline int load_src(const int* ei, int E, int e, int f64) {
  return f64 ? ei[2 * e] : ei[e];
}
__device__ inline int load_dst(const int* ei, int E, int e, int f64) {
  return f64 ? ei[2 * (E + e)] : ei[E + e];
}

// ---------------- CSR build ----------------

__global__ void hist_k(const int* __restrict__ ei, int* __restrict__ cnt, int E,
                       const int* __restrict__ flag) {
  int e = blockIdx.x * blockDim.x + threadIdx.x;
  if (e >= E) return;
  int f64 = *flag;
  int d = load_dst(ei, E, e, f64);
  atomicAdd(&cnt[d], 1);
}

__global__ void scan1(const int* __restrict__ cnt, int* __restrict__ offs,
                      int* __restrict__ bsums, float* __restrict__ inv, int n) {
  __shared__ int s[256];
  int i = blockIdx.x * 256 + threadIdx.x;
  int v = (i < n) ? cnt[i] : 0;
  if (i < n) inv[i] = 1.0f / (float)((v > 1) ? v : 1);
  s[threadIdx.x] = v;
  __syncthreads();
  for (int d = 1; d < 256; d <<= 1) {
    int t = (threadIdx.x >= d) ? s[threadIdx.x - d] : 0;
    __syncthreads();
    s[threadIdx.x] += t;
    __syncthreads();
  }
  if (i < n) offs[i] = s[threadIdx.x] - v;   // exclusive
  if (threadIdx.x == 255) bsums[blockIdx.x] = s[255];
}

__global__ void scan2(int* __restrict__ bsums, int nb) {
  __shared__ int s[512];
  int v = (threadIdx.x < nb) ? bsums[threadIdx.x] : 0;
  s[threadIdx.x] = v;
  __syncthreads();
  for (int d = 1; d < 512; d <<= 1) {
    int t = (threadIdx.x >= d) ? s[threadIdx.x - d] : 0;
    __syncthreads();
    s[threadIdx.x] += t;
    __syncthreads();
  }
  if (threadIdx.x < nb) bsums[threadIdx.x] = s[threadIdx.x] - v;  // exclusive
}

__global__ void scan3(int* __restrict__ offs, const int* __restrict__ bsums,
                      int* __restrict__ cursor, int n) {
  int i = blockIdx.x * 256 + threadIdx.x;
  if (i >= n) return;
  int v = offs[i] + bsums[blockIdx.x];
  offs[i] = v;
  cursor[i] = v;
}

__global__ void fill_k(const int* __restrict__ ei, int* __restrict__ cursor,
                       int* __restrict__ csr, int E, const int* __restrict__ flag) {
  int e = blockIdx.x * blockDim.x + threadIdx.x;
  if (e >= E) return;
  int f64 = *flag;
  int s = load_src(ei, E, e, f64);
  int d = load_dst(ei, E, e, f64);
  int p = atomicAdd(&cursor[d], 1);
  csr[p] = s;
}

// ---------------- dual GEMM: Z = A@Wl^T (bf16), Y = A@Wr^T (f32) ----------------
// mfma_f32_16x16x32_bf16 layouts (HW-verified per guide):
//   A frag: A[m = lane&15][k = (lane>>4)*8 + j]
//   B frag: B[k = (lane>>4)*8 + j][n = lane&15]; B = W^T so lane reads W[n0+n][k-run]
//   C/D   : col = lane&15, row = (lane>>4)*4 + reg
template <int AF32>
__global__ __launch_bounds__(256) void dual_gemm(
    const void* __restrict__ Av,
    const float* __restrict__ Wl, const float* __restrict__ Wr,
    unsigned short* __restrict__ Z, float* __restrict__ Y, int n) {
  // frag-major weight staging: chunk c = (s*8 + jt)*4 + q, then 16 lanes x 8 bf16
  __shared__ unsigned short wsh[2 * 16384];  // 64 KiB
  const int tid = threadIdx.x;

  for (int mi = 0; mi < 2; ++mi) {
    const float* W = mi ? Wr : Wl;
#pragma unroll
    for (int it = 0; it < 8; ++it) {
      int id = it * 256 + tid;       // 0..2047 chunks of 8
      int j = id >> 4;               // W row (output col) 0..127
      int kc = id & 15;              // which 8-wide k chunk
      int s = kc >> 2, q = kc & 3;
      int jt = j >> 4, nn2 = j & 15;
      int c = (s * 8 + jt) * 4 + q;
      const float* src = W + j * 128 + kc * 8;
      union { unsigned short u[8]; uint4 v; } t;
#pragma unroll
      for (int k = 0; k < 8; ++k) t.u[k] = f2bf(src[k]);
      *(uint4*)(wsh + mi * 16384 + (c * 16 + nn2) * 8) = t.v;
    }
  }
  __syncthreads();

  const int lane = tid & 63;
  const int wave = tid >> 6;
  const int nn = lane & 15;
  const int quad = lane >> 4;
  const int rowbase = blockIdx.x * 64 + wave * 16;

  int nodeA = rowbase + nn;
  if (nodeA > n - 1) nodeA = n - 1;

  short8 a[4];
#pragma unroll
  for (int s = 0; s < 4; ++s) {
    if (AF32) {
      const float* ap = (const float*)Av + (size_t)nodeA * 128 + s * 32 + quad * 8;
      union { unsigned short u[8]; short8 v; } t;
#pragma unroll
      for (int k = 0; k < 8; ++k) t.u[k] = f2bf(ap[k]);
      a[s] = t.v;
    } else {
      a[s] = *(const short8*)((const unsigned short*)Av + (size_t)nodeA * 128 + s * 32 + quad * 8);
    }
  }

  f32x4 accl[8], accr[8];
#pragma unroll
  for (int jt = 0; jt < 8; ++jt) {
    accl[jt] = (f32x4){0.f, 0.f, 0.f, 0.f};
    accr[jt] = (f32x4){0.f, 0.f, 0.f, 0.f};
  }

#pragma unroll
  for (int jt = 0; jt < 8; ++jt) {
#pragma unroll
    for (int s = 0; s < 4; ++s) {
      int c = (s * 8 + jt) * 4 + quad;
      short8 bl = *(const short8*)(wsh + (c * 16 + nn) * 8);
      short8 br = *(const short8*)(wsh + 16384 + (c * 16 + nn) * 8);
      accl[jt] = __builtin_amdgcn_mfma_f32_16x16x32_bf16(a[s], bl, accl[jt], 0, 0, 0);
      accr[jt] = __builtin_amdgcn_mfma_f32_16x16x32_bf16(a[s], br, accr[jt], 0, 0, 0);
    }
  }

#pragma unroll
  for (int jt = 0; jt < 8; ++jt) {
#pragma unroll
    for (int r = 0; r < 4; ++r) {
      int ro = rowbase + quad * 4 + r;
      if (ro < n) {
        int col = jt * 16 + nn;
        Y[(size_t)ro * 128 + col] = accr[jt][r];
        Z[(size_t)ro * 128 + col] = f2bf(accl[jt][r]);
      }
    }
  }
}

// ---------------- fused mean-aggregate + bias + self + (relu) ----------------
// one wave per node; out = agg(Z[nbrs])*inv + bias + Y[node]
template <int RELU>
__global__ __launch_bounds__(256) void agg_fuse(
    const unsigned short* __restrict__ Z, const float* __restrict__ Y,
    const float* __restrict__ bias, const float* __restrict__ inv,
    const int* __restrict__ offs, const int* __restrict__ cnt,
    const int* __restrict__ csr, float* __restrict__ outp, int n) {
  int gw = (int)((blockIdx.x * 256 + threadIdx.x) >> 6);
  int lane = threadIdx.x & 63;
  if (gw >= n) return;
  int deg = cnt[gw];
  int start = offs[gw];
  float a0 = 0.f, a1 = 0.f;
  int c0 = lane * 2;
  for (int base = 0; base < deg; base += 64) {
    int m = deg - base;
    if (m > 64) m = 64;
    int idx = (lane < m) ? csr[start + base + lane] : 0;
    for (int i = 0; i < m; ++i) {
      int nb = __shfl(idx, i);
      unsigned v = *(const unsigned*)(Z + (size_t)nb * 128 + c0);
      a0 += bf2f((unsigned short)(v & 0xffffu));
      a1 += bf2f((unsigned short)(v >> 16));
    }
  }
  float s = inv[gw];
  float o0 = fmaf(a0, s, bias[c0] + Y[(size_t)gw * 128 + c0]);
  float o1 = fmaf(a1, s, bias[c0 + 1] + Y[(size_t)gw * 128 + c0 + 1]);
  if (RELU) { o0 = fmaxf(o0, 0.f); o1 = fmaxf(o1, 0.f); }
  *(float2*)(outp + (size_t)gw * 128 + c0) = make_float2(o0, o1);
}

// ---------------- launch ----------------

extern "C" void kernel_launch(void* const* d_in, const int* in_sizes, int n_in,
                              void* d_out, int out_size, void* d_ws, size_t ws_size,
                              hipStream_t stream) {
  const float* x = (const float*)d_in[0];
  const int* ei = (const int*)d_in[1];
  const float* W1l = (const float*)d_in[2];
  const float* b1 = (const float*)d_in[3];
  const float* W1r = (const float*)d_in[4];
  const float* W2l = (const float*)d_in[5];
  const float* b2 = (const float*)d_in[6];
  const float* W2r = (const float*)d_in[7];
  float* out = (float*)d_out;

  const int N = in_sizes[0] / 128;
  const int E = in_sizes[1] / 2;

  char* p = (char*)d_ws;
  auto alloc = [&](size_t bytes) {
    char* r = p;
    p += (bytes + 255) & ~(size_t)255;
    return r;
  };
  int* flag = (int*)alloc(256);
  int* cnt = (int*)alloc((size_t)N * 4);
  int* offs = (int*)alloc((size_t)N * 4);
  int* cursor = (int*)alloc((size_t)N * 4);
  float* inv = (float*)alloc((size_t)N * 4);
  int* bsums = (int*)alloc(4096);
  int* csr = (int*)alloc((size_t)E * 4);
  unsigned short* zb = (unsigned short*)alloc((size_t)N * 128 * 2);  // 25.6 MB
  float* yf = (float*)alloc((size_t)N * 128 * 4);                    // 51.2 MB

  hipMemsetAsync(cnt, 0, (size_t)N * 4, stream);

  const int TB = 256;
  detect_k<<<1, 256, 0, stream>>>(ei, E, flag);
  hist_k<<<(E + TB - 1) / TB, TB, 0, stream>>>(ei, cnt, E, flag);
  const int nb1 = (N + 255) / 256;
  scan1<<<nb1, 256, 0, stream>>>(cnt, offs, bsums, inv, N);
  scan2<<<1, 512, 0, stream>>>(bsums, nb1);
  scan3<<<nb1, 256, 0, stream>>>(offs, bsums, cursor, N);
  fill_k<<<(E + TB - 1) / TB, TB, 0, stream>>>(ei, cursor, csr, E, flag);

  const int gb = (N + 63) / 64;
  const int ab = (int)(((size_t)N * 64 + TB - 1) / TB);

  // layer 1: h (f32, post-relu) staged in d_out
  dual_gemm<1><<<gb, 256, 0, stream>>>((const void*)x, W1l, W1r, zb, yf, N);
  agg_fuse<1><<<ab, 256, 0, stream>>>(zb, yf, b1, inv, offs, cnt, csr, out, N);
  // layer 2: reads h from d_out, overwrites d_out with final result
  dual_gemm<1><<<gb, 256, 0, stream>>>((const void*)out, W2l, W2r, zb, yf, N);
  agg_fuse<0><<<ab, 256, 0, stream>>>(zb, yf, b2, inv, offs, cnt, csr, out, N);
}

// Round 3
// 497.775 us; speedup vs baseline: 1.1602x; 1.1602x over previous
//
#include <hip/hip_runtime.h>

typedef __attribute__((ext_vector_type(8))) short short8;
typedef __attribute__((ext_vector_type(4))) float f32x4;

#define NBMAX 512

__device__ inline unsigned short f2bf(float f) {
  union { float f; unsigned u; } v; v.f = f;
  unsigned r = v.u + 0x7fffu + ((v.u >> 16) & 1u);
  return (unsigned short)(r >> 16);
}
__device__ inline float bf2f(unsigned short b) {
  union { unsigned u; float f; } v; v.u = ((unsigned)b) << 16;
  return v.f;
}

// ---------------- edge dtype detection ----------------
__global__ void detect_k(const int* __restrict__ ei, int E, int* __restrict__ flag) {
  __shared__ int s;
  if (threadIdx.x == 0) s = 0;
  __syncthreads();
  int acc = 0;
  for (int i = threadIdx.x; i < 1024; i += 256) {
    int idx = 2 * i + 1;
    if (idx < 2 * E) acc |= ei[idx];
  }
  if (acc) atomicOr(&s, 1);
  __syncthreads();
  if (threadIdx.x == 0) *flag = (s == 0) ? 1 : 0;  // 1 = int64 layout
}

__device__ inline int load_src(const int* ei, int E, int e, int f64) {
  return f64 ? ei[2 * e] : ei[e];
}
__device__ inline int load_dst(const int* ei, int E, int e, int f64) {
  return f64 ? ei[2 * (E + e)] : ei[E + e];
}

// ---------------- CSR build ----------------

__global__ void hist_k(const int* __restrict__ ei, int* __restrict__ cnt, int E,
                       const int* __restrict__ flag) {
  int e = blockIdx.x * blockDim.x + threadIdx.x;
  if (e >= E) return;
  int f64 = *flag;
  int d = load_dst(ei, E, e, f64);
  atomicAdd(&cnt[d], 1);
}

__global__ void scan1(const int* __restrict__ cnt, int* __restrict__ offs,
                      int* __restrict__ bsums, float* __restrict__ inv, int n) {
  __shared__ int s[256];
  int i = blockIdx.x * 256 + threadIdx.x;
  int v = (i < n) ? cnt[i] : 0;
  if (i < n) inv[i] = 1.0f / (float)((v > 1) ? v : 1);
  s[threadIdx.x] = v;
  __syncthreads();
  for (int d = 1; d < 256; d <<= 1) {
    int t = (threadIdx.x >= d) ? s[threadIdx.x - d] : 0;
    __syncthreads();
    s[threadIdx.x] += t;
    __syncthreads();
  }
  if (i < n) offs[i] = s[threadIdx.x] - v;   // exclusive
  if (threadIdx.x == 255) bsums[blockIdx.x] = s[255];
}

__global__ void scan2(int* __restrict__ bsums, int nb) {
  __shared__ int s[512];
  int v = (threadIdx.x < nb) ? bsums[threadIdx.x] : 0;
  s[threadIdx.x] = v;
  __syncthreads();
  for (int d = 1; d < 512; d <<= 1) {
    int t = (threadIdx.x >= d) ? s[threadIdx.x - d] : 0;
    __syncthreads();
    s[threadIdx.x] += t;
    __syncthreads();
  }
  if (threadIdx.x < nb) bsums[threadIdx.x] = s[threadIdx.x] - v;  // exclusive
}

__global__ void scan3(int* __restrict__ offs, const int* __restrict__ bsums, int n) {
  int i = blockIdx.x * 256 + threadIdx.x;
  if (i >= n) return;
  offs[i] += bsums[blockIdx.x];
}

__global__ void binit_k(const int* __restrict__ offs, int* __restrict__ bcur,
                        int nb, int N) {
  int b = blockIdx.x * blockDim.x + threadIdx.x;
  if (b >= nb) return;
  bcur[b] = offs[b * 256];
}

// Phase A: bucket = dst>>8; LDS histogram, bulk-reserve, clustered append of (src,dst)
__global__ __launch_bounds__(256) void bucket_scatter(
    const int* __restrict__ ei, int E, const int* __restrict__ flag,
    int* __restrict__ bcur, int2* __restrict__ stage) {
  __shared__ int lcnt[NBMAX];
  __shared__ int lbase[NBMAX];
  const int t = threadIdx.x;
  for (int i = t; i < NBMAX; i += 256) lcnt[i] = 0;
  __syncthreads();
  const int e0 = blockIdx.x * 4096;
  const int f64 = *flag;
  int srcs[16], dsts[16], bks[16];
#pragma unroll
  for (int i = 0; i < 16; ++i) {
    int e = e0 + i * 256 + t;
    if (e < E) {
      srcs[i] = load_src(ei, E, e, f64);
      int d = load_dst(ei, E, e, f64);
      dsts[i] = d;
      bks[i] = d >> 8;
      atomicAdd(&lcnt[d >> 8], 1);
    } else {
      bks[i] = -1;
    }
  }
  __syncthreads();
  for (int i = t; i < NBMAX; i += 256) {
    int c = lcnt[i];
    lbase[i] = c ? atomicAdd(&bcur[i], c) : 0;
  }
  __syncthreads();
  for (int i = t; i < NBMAX; i += 256) lcnt[i] = 0;
  __syncthreads();
#pragma unroll
  for (int i = 0; i < 16; ++i) {
    int b = bks[i];
    if (b >= 0) {
      int r = atomicAdd(&lcnt[b], 1);
      stage[lbase[b] + r] = make_int2(srcs[i], dsts[i]);
    }
  }
}

// Phase B: one WG per bucket; LDS per-node cursors; csr writes stay in a ~16KB window
__global__ __launch_bounds__(256) void bucket_fill(
    const int2* __restrict__ stage, const int* __restrict__ offs,
    int* __restrict__ csr, int N, int E) {
  __shared__ int lcur[256];
  const int b = blockIdx.x;
  const int n0 = b * 256;
  const int t = threadIdx.x;
  int node = n0 + t;
  lcur[t] = (node < N) ? offs[node] : 0;
  __syncthreads();
  int rstart = lcur[0];
  int rend = (n0 + 256 < N) ? offs[n0 + 256] : E;
  if (n0 + 256 < N) {
    // rend read again by all threads (broadcast); ok
  }
  for (int i = rstart + t; i < rend; i += 256) {
    int2 sd = stage[i];
    int p = atomicAdd(&lcur[sd.y & 255], 1);
    csr[p] = sd.x;
  }
}

// ---------------- dual GEMM: Z = A@Wl^T (bf16), Y = A@Wr^T (f32) ----------------
template <int AF32>
__global__ __launch_bounds__(256) void dual_gemm(
    const void* __restrict__ Av,
    const float* __restrict__ Wl, const float* __restrict__ Wr,
    unsigned short* __restrict__ Z, float* __restrict__ Y, int n) {
  __shared__ unsigned short wsh[2 * 16384];  // 64 KiB
  const int tid = threadIdx.x;

  for (int mi = 0; mi < 2; ++mi) {
    const float* W = mi ? Wr : Wl;
#pragma unroll
    for (int it = 0; it < 8; ++it) {
      int id = it * 256 + tid;
      int j = id >> 4;
      int kc = id & 15;
      int s = kc >> 2, q = kc & 3;
      int jt = j >> 4, nn2 = j & 15;
      int c = (s * 8 + jt) * 4 + q;
      const float* src = W + j * 128 + kc * 8;
      union { unsigned short u[8]; uint4 v; } t;
#pragma unroll
      for (int k = 0; k < 8; ++k) t.u[k] = f2bf(src[k]);
      *(uint4*)(wsh + mi * 16384 + (c * 16 + nn2) * 8) = t.v;
    }
  }
  __syncthreads();

  const int lane = tid & 63;
  const int wave = tid >> 6;
  const int nn = lane & 15;
  const int quad = lane >> 4;
  const int rowbase = blockIdx.x * 64 + wave * 16;

  int nodeA = rowbase + nn;
  if (nodeA > n - 1) nodeA = n - 1;

  short8 a[4];
#pragma unroll
  for (int s = 0; s < 4; ++s) {
    if (AF32) {
      const float* ap = (const float*)Av + (size_t)nodeA * 128 + s * 32 + quad * 8;
      union { unsigned short u[8]; short8 v; } t;
#pragma unroll
      for (int k = 0; k < 8; ++k) t.u[k] = f2bf(ap[k]);
      a[s] = t.v;
    } else {
      a[s] = *(const short8*)((const unsigned short*)Av + (size_t)nodeA * 128 + s * 32 + quad * 8);
    }
  }

  f32x4 accl[8], accr[8];
#pragma unroll
  for (int jt = 0; jt < 8; ++jt) {
    accl[jt] = (f32x4){0.f, 0.f, 0.f, 0.f};
    accr[jt] = (f32x4){0.f, 0.f, 0.f, 0.f};
  }

#pragma unroll
  for (int jt = 0; jt < 8; ++jt) {
#pragma unroll
    for (int s = 0; s < 4; ++s) {
      int c = (s * 8 + jt) * 4 + quad;
      short8 bl = *(const short8*)(wsh + (c * 16 + nn) * 8);
      short8 br = *(const short8*)(wsh + 16384 + (c * 16 + nn) * 8);
      accl[jt] = __builtin_amdgcn_mfma_f32_16x16x32_bf16(a[s], bl, accl[jt], 0, 0, 0);
      accr[jt] = __builtin_amdgcn_mfma_f32_16x16x32_bf16(a[s], br, accr[jt], 0, 0, 0);
    }
  }

#pragma unroll
  for (int jt = 0; jt < 8; ++jt) {
#pragma unroll
    for (int r = 0; r < 4; ++r) {
      int ro = rowbase + quad * 4 + r;
      if (ro < n) {
        int col = jt * 16 + nn;
        Y[(size_t)ro * 128 + col] = accr[jt][r];
        Z[(size_t)ro * 128 + col] = f2bf(accl[jt][r]);
      }
    }
  }
}

// ---------------- fused mean-aggregate + bias + self + (relu) ----------------
template <int RELU>
__global__ __launch_bounds__(256) void agg_fuse(
    const unsigned short* __restrict__ Z, const float* __restrict__ Y,
    const float* __restrict__ bias, const float* __restrict__ inv,
    const int* __restrict__ offs, const int* __restrict__ cnt,
    const int* __restrict__ csr, float* __restrict__ outp, int n) {
  int gw = (int)((blockIdx.x * 256 + threadIdx.x) >> 6);
  int lane = threadIdx.x & 63;
  if (gw >= n) return;
  int deg = cnt[gw];
  int start = offs[gw];
  float a0 = 0.f, a1 = 0.f;
  int c0 = lane * 2;
  for (int base = 0; base < deg; base += 64) {
    int m = deg - base;
    if (m > 64) m = 64;
    int idx = (lane < m) ? csr[start + base + lane] : 0;
    for (int i = 0; i < m; ++i) {
      int nb = __shfl(idx, i);
      unsigned v = *(const unsigned*)(Z + (size_t)nb * 128 + c0);
      a0 += bf2f((unsigned short)(v & 0xffffu));
      a1 += bf2f((unsigned short)(v >> 16));
    }
  }
  float s = inv[gw];
  float o0 = fmaf(a0, s, bias[c0] + Y[(size_t)gw * 128 + c0]);
  float o1 = fmaf(a1, s, bias[c0 + 1] + Y[(size_t)gw * 128 + c0 + 1]);
  if (RELU) { o0 = fmaxf(o0, 0.f); o1 = fmaxf(o1, 0.f); }
  *(float2*)(outp + (size_t)gw * 128 + c0) = make_float2(o0, o1);
}

// ---------------- launch ----------------

extern "C" void kernel_launch(void* const* d_in, const int* in_sizes, int n_in,
                              void* d_out, int out_size, void* d_ws, size_t ws_size,
                              hipStream_t stream) {
  const float* x = (const float*)d_in[0];
  const int* ei = (const int*)d_in[1];
  const float* W1l = (const float*)d_in[2];
  const float* b1 = (const float*)d_in[3];
  const float* W1r = (const float*)d_in[4];
  const float* W2l = (const float*)d_in[5];
  const float* b2 = (const float*)d_in[6];
  const float* W2r = (const float*)d_in[7];
  float* out = (float*)d_out;

  const int N = in_sizes[0] / 128;
  const int E = in_sizes[1] / 2;
  const int nb = (N + 255) / 256;   // buckets of 256 nodes; must be <= NBMAX

  char* p = (char*)d_ws;
  auto alloc = [&](size_t bytes) {
    char* r = p;
    p += (bytes + 255) & ~(size_t)255;
    return r;
  };
  int* flag = (int*)alloc(256);
  int* cnt = (int*)alloc((size_t)N * 4);
  int* offs = (int*)alloc((size_t)N * 4);
  float* inv = (float*)alloc((size_t)N * 4);
  int* bsums = (int*)alloc(4096);
  int* bcur = (int*)alloc((size_t)NBMAX * 4);
  int* csr = (int*)alloc((size_t)E * 4);
  unsigned short* zb = (unsigned short*)alloc((size_t)N * 128 * 2);  // 25.6 MB
  float* yf = (float*)alloc((size_t)N * 128 * 4);                    // 51.2 MB
  int2* stage = (int2*)yf;  // 12.8 MB alias — dead before dual_gemm writes yf

  hipMemsetAsync(cnt, 0, (size_t)N * 4, stream);

  const int TB = 256;
  detect_k<<<1, 256, 0, stream>>>(ei, E, flag);
  hist_k<<<(E + TB - 1) / TB, TB, 0, stream>>>(ei, cnt, E, flag);
  const int nb1 = (N + 255) / 256;
  scan1<<<nb1, 256, 0, stream>>>(cnt, offs, bsums, inv, N);
  scan2<<<1, 512, 0, stream>>>(bsums, nb1);
  scan3<<<nb1, 256, 0, stream>>>(offs, bsums, N);
  binit_k<<<(nb + 255) / 256, 256, 0, stream>>>(offs, bcur, nb, N);
  bucket_scatter<<<(E + 4095) / 4096, 256, 0, stream>>>(ei, E, flag, bcur, stage);
  bucket_fill<<<nb, 256, 0, stream>>>(stage, offs, csr, N, E);

  const int gb = (N + 63) / 64;
  const int ab = (int)(((size_t)N * 64 + TB - 1) / TB);

  // layer 1: h (f32, post-relu) staged in d_out
  dual_gemm<1><<<gb, 256, 0, stream>>>((const void*)x, W1l, W1r, zb, yf, N);
  agg_fuse<1><<<ab, 256, 0, stream>>>(zb, yf, b1, inv, offs, cnt, csr, out, N);
  // layer 2: reads h from d_out, overwrites d_out with final result
  dual_gemm<1><<<gb, 256, 0, stream>>>((const void*)out, W2l, W2r, zb, yf, N);
  agg_fuse<0><<<ab, 256, 0, stream>>>(zb, yf, b2, inv, offs, cnt, csr, out, N);
}

// Round 4
// 417.245 us; speedup vs baseline: 1.3841x; 1.1930x over previous
//
#include <hip/hip_runtime.h>

typedef __attribute__((ext_vector_type(8))) short short8;
typedef __attribute__((ext_vector_type(4))) float f32x4;

#define NBMAX 512

__device__ inline unsigned short f2bf(float f) {
  union { float f; unsigned u; } v; v.f = f;
  unsigned r = v.u + 0x7fffu + ((v.u >> 16) & 1u);
  return (unsigned short)(r >> 16);
}
__device__ inline float bf2f(unsigned short b) {
  union { unsigned u; float f; } v; v.u = ((unsigned)b) << 16;
  return v.f;
}

// ---------------- edge dtype detection ----------------
__global__ void detect_k(const int* __restrict__ ei, int E, int* __restrict__ flag) {
  __shared__ int s;
  if (threadIdx.x == 0) s = 0;
  __syncthreads();
  int acc = 0;
  for (int i = threadIdx.x; i < 1024; i += 256) {
    int idx = 2 * i + 1;
    if (idx < 2 * E) acc |= ei[idx];
  }
  if (acc) atomicOr(&s, 1);
  __syncthreads();
  if (threadIdx.x == 0) *flag = (s == 0) ? 1 : 0;  // 1 = int64 layout
}

__device__ inline int load_src(const int* ei, int E, int e, int f64) {
  return f64 ? ei[2 * e] : ei[e];
}
__device__ inline int load_dst(const int* ei, int E, int e, int f64) {
  return f64 ? ei[2 * (E + e)] : ei[E + e];
}

// ---------------- CSR build ----------------

__global__ void hist_k(const int* __restrict__ ei, int* __restrict__ cnt, int E,
                       const int* __restrict__ flag) {
  int e = blockIdx.x * blockDim.x + threadIdx.x;
  if (e >= E) return;
  int f64 = *flag;
  int d = load_dst(ei, E, e, f64);
  atomicAdd(&cnt[d], 1);
}

__global__ void scan1(const int* __restrict__ cnt, int* __restrict__ offs,
                      int* __restrict__ bsums, float* __restrict__ inv, int n) {
  __shared__ int s[256];
  int i = blockIdx.x * 256 + threadIdx.x;
  int v = (i < n) ? cnt[i] : 0;
  if (i < n) inv[i] = 1.0f / (float)((v > 1) ? v : 1);
  s[threadIdx.x] = v;
  __syncthreads();
  for (int d = 1; d < 256; d <<= 1) {
    int t = (threadIdx.x >= d) ? s[threadIdx.x - d] : 0;
    __syncthreads();
    s[threadIdx.x] += t;
    __syncthreads();
  }
  if (i < n) offs[i] = s[threadIdx.x] - v;   // exclusive
  if (threadIdx.x == 255) bsums[blockIdx.x] = s[255];
}

__global__ void scan2(int* __restrict__ bsums, int nb) {
  __shared__ int s[512];
  int v = (threadIdx.x < nb) ? bsums[threadIdx.x] : 0;
  s[threadIdx.x] = v;
  __syncthreads();
  for (int d = 1; d < 512; d <<= 1) {
    int t = (threadIdx.x >= d) ? s[threadIdx.x - d] : 0;
    __syncthreads();
    s[threadIdx.x] += t;
    __syncthreads();
  }
  if (threadIdx.x < nb) bsums[threadIdx.x] = s[threadIdx.x] - v;  // exclusive
}

__global__ void scan3(int* __restrict__ offs, const int* __restrict__ bsums, int n) {
  int i = blockIdx.x * 256 + threadIdx.x;
  if (i >= n) return;
  offs[i] += bsums[blockIdx.x];
}

__global__ void binit_k(const int* __restrict__ offs, int* __restrict__ bcur,
                        int nb, int N) {
  int b = blockIdx.x * blockDim.x + threadIdx.x;
  if (b >= nb) return;
  bcur[b] = offs[b * 256];
}

// Phase A: bucket = dst>>8; LDS histogram, bulk-reserve, clustered append of (src,dst)
__global__ __launch_bounds__(256) void bucket_scatter(
    const int* __restrict__ ei, int E, const int* __restrict__ flag,
    int* __restrict__ bcur, int2* __restrict__ stage) {
  __shared__ int lcnt[NBMAX];
  __shared__ int lbase[NBMAX];
  const int t = threadIdx.x;
  for (int i = t; i < NBMAX; i += 256) lcnt[i] = 0;
  __syncthreads();
  const int e0 = blockIdx.x * 4096;
  const int f64 = *flag;
  int srcs[16], dsts[16], bks[16];
#pragma unroll
  for (int i = 0; i < 16; ++i) {
    int e = e0 + i * 256 + t;
    if (e < E) {
      srcs[i] = load_src(ei, E, e, f64);
      int d = load_dst(ei, E, e, f64);
      dsts[i] = d;
      bks[i] = d >> 8;
      atomicAdd(&lcnt[d >> 8], 1);
    } else {
      bks[i] = -1;
    }
  }
  __syncthreads();
  for (int i = t; i < NBMAX; i += 256) {
    int c = lcnt[i];
    lbase[i] = c ? atomicAdd(&bcur[i], c) : 0;
  }
  __syncthreads();
  for (int i = t; i < NBMAX; i += 256) lcnt[i] = 0;
  __syncthreads();
#pragma unroll
  for (int i = 0; i < 16; ++i) {
    int b = bks[i];
    if (b >= 0) {
      int r = atomicAdd(&lcnt[b], 1);
      stage[lbase[b] + r] = make_int2(srcs[i], dsts[i]);
    }
  }
}

// Phase B: one WG per bucket; LDS per-node cursors; csr writes stay in a ~16KB window
__global__ __launch_bounds__(256) void bucket_fill(
    const int2* __restrict__ stage, const int* __restrict__ offs,
    int* __restrict__ csr, int N, int E) {
  __shared__ int lcur[256];
  const int b = blockIdx.x;
  const int n0 = b * 256;
  const int t = threadIdx.x;
  int node = n0 + t;
  lcur[t] = (node < N) ? offs[node] : 0;
  __syncthreads();
  int rstart = lcur[0];
  int rend = (n0 + 256 < N) ? offs[n0 + 256] : E;
  for (int i = rstart + t; i < rend; i += 256) {
    int2 sd = stage[i];
    int p = atomicAdd(&lcur[sd.y & 255], 1);
    csr[p] = sd.x;
  }
}

// ---------------- dual GEMM: Z = A@Wl^T (bf16), Y = A@Wr^T (f32) ----------------
template <int AF32>
__global__ __launch_bounds__(256) void dual_gemm(
    const void* __restrict__ Av,
    const float* __restrict__ Wl, const float* __restrict__ Wr,
    unsigned short* __restrict__ Z, float* __restrict__ Y, int n) {
  __shared__ unsigned short wsh[2 * 16384];  // 64 KiB
  const int tid = threadIdx.x;

  for (int mi = 0; mi < 2; ++mi) {
    const float* W = mi ? Wr : Wl;
#pragma unroll
    for (int it = 0; it < 8; ++it) {
      int id = it * 256 + tid;
      int j = id >> 4;
      int kc = id & 15;
      int s = kc >> 2, q = kc & 3;
      int jt = j >> 4, nn2 = j & 15;
      int c = (s * 8 + jt) * 4 + q;
      const float* src = W + j * 128 + kc * 8;
      union { unsigned short u[8]; uint4 v; } t;
#pragma unroll
      for (int k = 0; k < 8; ++k) t.u[k] = f2bf(src[k]);
      *(uint4*)(wsh + mi * 16384 + (c * 16 + nn2) * 8) = t.v;
    }
  }
  __syncthreads();

  const int lane = tid & 63;
  const int wave = tid >> 6;
  const int nn = lane & 15;
  const int quad = lane >> 4;
  const int rowbase = blockIdx.x * 64 + wave * 16;

  int nodeA = rowbase + nn;
  if (nodeA > n - 1) nodeA = n - 1;

  short8 a[4];
#pragma unroll
  for (int s = 0; s < 4; ++s) {
    if (AF32) {
      const float* ap = (const float*)Av + (size_t)nodeA * 128 + s * 32 + quad * 8;
      union { unsigned short u[8]; short8 v; } t;
#pragma unroll
      for (int k = 0; k < 8; ++k) t.u[k] = f2bf(ap[k]);
      a[s] = t.v;
    } else {
      a[s] = *(const short8*)((const unsigned short*)Av + (size_t)nodeA * 128 + s * 32 + quad * 8);
    }
  }

  f32x4 accl[8], accr[8];
#pragma unroll
  for (int jt = 0; jt < 8; ++jt) {
    accl[jt] = (f32x4){0.f, 0.f, 0.f, 0.f};
    accr[jt] = (f32x4){0.f, 0.f, 0.f, 0.f};
  }

#pragma unroll
  for (int jt = 0; jt < 8; ++jt) {
#pragma unroll
    for (int s = 0; s < 4; ++s) {
      int c = (s * 8 + jt) * 4 + quad;
      short8 bl = *(const short8*)(wsh + (c * 16 + nn) * 8);
      short8 br = *(const short8*)(wsh + 16384 + (c * 16 + nn) * 8);
      accl[jt] = __builtin_amdgcn_mfma_f32_16x16x32_bf16(a[s], bl, accl[jt], 0, 0, 0);
      accr[jt] = __builtin_amdgcn_mfma_f32_16x16x32_bf16(a[s], br, accr[jt], 0, 0, 0);
    }
  }

#pragma unroll
  for (int jt = 0; jt < 8; ++jt) {
#pragma unroll
    for (int r = 0; r < 4; ++r) {
      int ro = rowbase + quad * 4 + r;
      if (ro < n) {
        int col = jt * 16 + nn;
        Y[(size_t)ro * 128 + col] = accr[jt][r];
        Z[(size_t)ro * 128 + col] = f2bf(accl[jt][r]);
      }
    }
  }
}

// ---------------- fused mean-aggregate + bias + self + (relu) ----------------
// one wave per node; 4 edge-slots x 16 column-lanes; 16B gathers, 4 in flight
template <int RELU>
__global__ __launch_bounds__(256) void agg_fuse(
    const unsigned short* __restrict__ Z, const float* __restrict__ Y,
    const float* __restrict__ bias, const float* __restrict__ inv,
    const int* __restrict__ offs, const int* __restrict__ cnt,
    const int* __restrict__ csr, float* __restrict__ outp, int n) {
  int gw = (int)((blockIdx.x * 256 + threadIdx.x) >> 6);
  if (gw >= n) return;
  const int lane = threadIdx.x & 63;
  const int g = lane >> 4;      // edge slot 0..3
  const int l = lane & 15;      // column chunk: columns l*8 .. l*8+7
  int deg = cnt[gw];
  int start = offs[gw];
  float acc[8] = {0.f, 0.f, 0.f, 0.f, 0.f, 0.f, 0.f, 0.f};
  for (int base = 0; base < deg; base += 64) {
    int m = deg - base;
    if (m > 64) m = 64;
    int idx = (lane < m) ? csr[start + base + lane] : 0;
#pragma unroll 4
    for (int i = 0; i < m; i += 4) {
      int sl = i + g;
      int nb = __shfl(idx, sl);
      if (sl < m) {
        uint4 v = *(const uint4*)(Z + (size_t)nb * 128 + l * 8);
        acc[0] += bf2f((unsigned short)(v.x & 0xffffu));
        acc[1] += bf2f((unsigned short)(v.x >> 16));
        acc[2] += bf2f((unsigned short)(v.y & 0xffffu));
        acc[3] += bf2f((unsigned short)(v.y >> 16));
        acc[4] += bf2f((unsigned short)(v.z & 0xffffu));
        acc[5] += bf2f((unsigned short)(v.z >> 16));
        acc[6] += bf2f((unsigned short)(v.w & 0xffffu));
        acc[7] += bf2f((unsigned short)(v.w >> 16));
      }
    }
  }
  // reduce the 4 edge-slots (lanes differing in bits 4..5)
#pragma unroll
  for (int j = 0; j < 8; ++j) {
    acc[j] += __shfl_xor(acc[j], 16);
    acc[j] += __shfl_xor(acc[j], 32);
  }
  // epilogue: lane (g,l) owns columns c0 = l*8 + g*2, c0+1
  const int c0 = l * 8 + g * 2;
  float s = inv[gw];
  float2 yv = *(const float2*)(Y + (size_t)gw * 128 + c0);
  float o0 = fmaf(acc[g * 2 + 0], s, bias[c0] + yv.x);
  float o1 = fmaf(acc[g * 2 + 1], s, bias[c0 + 1] + yv.y);
  if (RELU) { o0 = fmaxf(o0, 0.f); o1 = fmaxf(o1, 0.f); }
  *(float2*)(outp + (size_t)gw * 128 + c0) = make_float2(o0, o1);
}

// ---------------- launch ----------------

extern "C" void kernel_launch(void* const* d_in, const int* in_sizes, int n_in,
                              void* d_out, int out_size, void* d_ws, size_t ws_size,
                              hipStream_t stream) {
  const float* x = (const float*)d_in[0];
  const int* ei = (const int*)d_in[1];
  const float* W1l = (const float*)d_in[2];
  const float* b1 = (const float*)d_in[3];
  const float* W1r = (const float*)d_in[4];
  const float* W2l = (const float*)d_in[5];
  const float* b2 = (const float*)d_in[6];
  const float* W2r = (const float*)d_in[7];
  float* out = (float*)d_out;

  const int N = in_sizes[0] / 128;
  const int E = in_sizes[1] / 2;
  const int nb = (N + 255) / 256;   // buckets of 256 nodes; must be <= NBMAX

  char* p = (char*)d_ws;
  auto alloc = [&](size_t bytes) {
    char* r = p;
    p += (bytes + 255) & ~(size_t)255;
    return r;
  };
  int* flag = (int*)alloc(256);
  int* cnt = (int*)alloc((size_t)N * 4);
  int* offs = (int*)alloc((size_t)N * 4);
  float* inv = (float*)alloc((size_t)N * 4);
  int* bsums = (int*)alloc(4096);
  int* bcur = (int*)alloc((size_t)NBMAX * 4);
  int* csr = (int*)alloc((size_t)E * 4);
  unsigned short* zb = (unsigned short*)alloc((size_t)N * 128 * 2);  // 25.6 MB
  float* yf = (float*)alloc((size_t)N * 128 * 4);                    // 51.2 MB
  int2* stage = (int2*)yf;  // 12.8 MB alias — dead before dual_gemm writes yf

  hipMemsetAsync(cnt, 0, (size_t)N * 4, stream);

  const int TB = 256;
  detect_k<<<1, 256, 0, stream>>>(ei, E, flag);
  hist_k<<<(E + TB - 1) / TB, TB, 0, stream>>>(ei, cnt, E, flag);
  const int nb1 = (N + 255) / 256;
  scan1<<<nb1, 256, 0, stream>>>(cnt, offs, bsums, inv, N);
  scan2<<<1, 512, 0, stream>>>(bsums, nb1);
  scan3<<<nb1, 256, 0, stream>>>(offs, bsums, N);
  binit_k<<<(nb + 255) / 256, 256, 0, stream>>>(offs, bcur, nb, N);
  bucket_scatter<<<(E + 4095) / 4096, 256, 0, stream>>>(ei, E, flag, bcur, stage);
  bucket_fill<<<nb, 256, 0, stream>>>(stage, offs, csr, N, E);

  const int gb = (N + 63) / 64;
  const int ab = (int)(((size_t)N * 64 + TB - 1) / TB);

  // layer 1: h (f32, post-relu) staged in d_out
  dual_gemm<1><<<gb, 256, 0, stream>>>((const void*)x, W1l, W1r, zb, yf, N);
  agg_fuse<1><<<ab, 256, 0, stream>>>(zb, yf, b1, inv, offs, cnt, csr, out, N);
  // layer 2: reads h from d_out, overwrites d_out with final result
  dual_gemm<1><<<gb, 256, 0, stream>>>((const void*)out, W2l, W2r, zb, yf, N);
  agg_fuse<0><<<ab, 256, 0, stream>>>(zb, yf, b2, inv, offs, cnt, csr, out, N);
}

// Round 7
// 403.722 us; speedup vs baseline: 1.4304x; 1.0335x over previous
//
#include <hip/hip_runtime.h>

typedef __attribute__((ext_vector_type(8))) short short8;
typedef __attribute__((ext_vector_type(4))) float f32x4;

#define NBMAX 512

__device__ inline unsigned short f2bf(float f) {
  union { float f; unsigned u; } v; v.f = f;
  unsigned r = v.u + 0x7fffu + ((v.u >> 16) & 1u);
  return (unsigned short)(r >> 16);
}
__device__ inline float bf2f(unsigned short b) {
  union { unsigned u; float f; } v; v.u = ((unsigned)b) << 16;
  return v.f;
}

__device__ inline void addv8(float (&a)[8], uint4 v) {
  a[0] += bf2f((unsigned short)(v.x & 0xffffu));
  a[1] += bf2f((unsigned short)(v.x >> 16));
  a[2] += bf2f((unsigned short)(v.y & 0xffffu));
  a[3] += bf2f((unsigned short)(v.y >> 16));
  a[4] += bf2f((unsigned short)(v.z & 0xffffu));
  a[5] += bf2f((unsigned short)(v.z >> 16));
  a[6] += bf2f((unsigned short)(v.w & 0xffffu));
  a[7] += bf2f((unsigned short)(v.w >> 16));
}

// ---------------- edge dtype detection ----------------
__global__ void detect_k(const int* __restrict__ ei, int E, int* __restrict__ flag) {
  __shared__ int s;
  if (threadIdx.x == 0) s = 0;
  __syncthreads();
  int acc = 0;
  for (int i = threadIdx.x; i < 1024; i += 256) {
    int idx = 2 * i + 1;
    if (idx < 2 * E) acc |= ei[idx];
  }
  if (acc) atomicOr(&s, 1);
  __syncthreads();
  if (threadIdx.x == 0) *flag = (s == 0) ? 1 : 0;  // 1 = int64 layout
}

__device__ inline int load_src(const int* ei, int E, int e, int f64) {
  return f64 ? ei[2 * e] : ei[e];
}
__device__ inline int load_dst(const int* ei, int E, int e, int f64) {
  return f64 ? ei[2 * (E + e)] : ei[E + e];
}

// ---------------- CSR build ----------------

__global__ void hist_k(const int* __restrict__ ei, int* __restrict__ cnt, int E,
                       const int* __restrict__ flag) {
  int e = blockIdx.x * blockDim.x + threadIdx.x;
  if (e >= E) return;
  int f64 = *flag;
  int d = load_dst(ei, E, e, f64);
  atomicAdd(&cnt[d], 1);
}

__global__ void scan1(const int* __restrict__ cnt, int* __restrict__ offs,
                      int* __restrict__ bsums, float* __restrict__ inv, int n) {
  __shared__ int s[256];
  int i = blockIdx.x * 256 + threadIdx.x;
  int v = (i < n) ? cnt[i] : 0;
  if (i < n) inv[i] = 1.0f / (float)((v > 1) ? v : 1);
  s[threadIdx.x] = v;
  __syncthreads();
  for (int d = 1; d < 256; d <<= 1) {
    int t = (threadIdx.x >= d) ? s[threadIdx.x - d] : 0;
    __syncthreads();
    s[threadIdx.x] += t;
    __syncthreads();
  }
  if (i < n) offs[i] = s[threadIdx.x] - v;   // exclusive within block
  if (threadIdx.x == 255) bsums[blockIdx.x] = s[255];
}

// fused: add block-prefix to offs, emit bucket cursors (bcur[b] = offs[b*256])
__global__ void scan23(int* __restrict__ offs, const int* __restrict__ bsums,
                       int* __restrict__ bcur, int n) {
  __shared__ int sred[256];
  const int B = blockIdx.x;
  const int t = threadIdx.x;
  int sum = 0;
  for (int i = t; i < B; i += 256) sum += bsums[i];
  sred[t] = sum;
  __syncthreads();
  for (int d = 128; d; d >>= 1) {
    if (t < d) sred[t] += sred[t + d];
    __syncthreads();
  }
  int prefix = sred[0];
  int i = B * 256 + t;
  if (i < n) offs[i] += prefix;
  if (t == 0) bcur[B] = prefix;
}

// Phase A: bucket = dst>>8; LDS histogram, bulk-reserve, clustered append of (src,dst)
__global__ __launch_bounds__(256) void bucket_scatter(
    const int* __restrict__ ei, int E, const int* __restrict__ flag,
    int* __restrict__ bcur, int2* __restrict__ stage) {
  __shared__ int lcnt[NBMAX];
  __shared__ int lbase[NBMAX];
  const int t = threadIdx.x;
  for (int i = t; i < NBMAX; i += 256) lcnt[i] = 0;
  __syncthreads();
  const int e0 = blockIdx.x * 4096;
  const int f64 = *flag;
  int srcs[16], dsts[16], bks[16];
#pragma unroll
  for (int i = 0; i < 16; ++i) {
    int e = e0 + i * 256 + t;
    if (e < E) {
      srcs[i] = load_src(ei, E, e, f64);
      int d = load_dst(ei, E, e, f64);
      dsts[i] = d;
      bks[i] = d >> 8;
      atomicAdd(&lcnt[d >> 8], 1);
    } else {
      bks[i] = -1;
    }
  }
  __syncthreads();
  for (int i = t; i < NBMAX; i += 256) {
    int c = lcnt[i];
    lbase[i] = c ? atomicAdd(&bcur[i], c) : 0;
  }
  __syncthreads();
  for (int i = t; i < NBMAX; i += 256) lcnt[i] = 0;
  __syncthreads();
#pragma unroll
  for (int i = 0; i < 16; ++i) {
    int b = bks[i];
    if (b >= 0) {
      int r = atomicAdd(&lcnt[b], 1);
      stage[lbase[b] + r] = make_int2(srcs[i], dsts[i]);
    }
  }
}

// Phase B: one WG per bucket; LDS per-node cursors; csr writes stay in a ~16KB window
__global__ __launch_bounds__(256) void bucket_fill(
    const int2* __restrict__ stage, const int* __restrict__ offs,
    int* __restrict__ csr, int N, int E) {
  __shared__ int lcur[256];
  const int b = blockIdx.x;
  const int n0 = b * 256;
  const int t = threadIdx.x;
  int node = n0 + t;
  lcur[t] = (node < N) ? offs[node] : 0;
  __syncthreads();
  int rstart = lcur[0];
  int rend = (n0 + 256 < N) ? offs[n0 + 256] : E;
  for (int i = rstart + t; i < rend; i += 256) {
    int2 sd = stage[i];
    int p = atomicAdd(&lcur[sd.y & 255], 1);
    csr[p] = sd.x;
  }
}

// ---------------- dual GEMM: Z = A@Wl^T (bf16), Y = A@Wr^T (f32) ----------------
template <int AF32>
__global__ __launch_bounds__(256) void dual_gemm(
    const void* __restrict__ Av,
    const float* __restrict__ Wl, const float* __restrict__ Wr,
    unsigned short* __restrict__ Z, float* __restrict__ Y, int n) {
  __shared__ unsigned short wsh[2 * 16384];  // 64 KiB
  const int tid = threadIdx.x;

  for (int mi = 0; mi < 2; ++mi) {
    const float* W = mi ? Wr : Wl;
#pragma unroll
    for (int it = 0; it < 8; ++it) {
      int id = it * 256 + tid;
      int j = id >> 4;
      int kc = id & 15;
      int s = kc >> 2, q = kc & 3;
      int jt = j >> 4, nn2 = j & 15;
      int c = (s * 8 + jt) * 4 + q;
      const float* src = W + j * 128 + kc * 8;
      union { unsigned short u[8]; uint4 v; } t;
#pragma unroll
      for (int k = 0; k < 8; ++k) t.u[k] = f2bf(src[k]);
      *(uint4*)(wsh + mi * 16384 + (c * 16 + nn2) * 8) = t.v;
    }
  }
  __syncthreads();

  const int lane = tid & 63;
  const int wave = tid >> 6;
  const int nn = lane & 15;
  const int quad = lane >> 4;
  const int rowbase = blockIdx.x * 64 + wave * 16;

  int nodeA = rowbase + nn;
  if (nodeA > n - 1) nodeA = n - 1;

  short8 a[4];
#pragma unroll
  for (int s = 0; s < 4; ++s) {
    if (AF32) {
      const float* ap = (const float*)Av + (size_t)nodeA * 128 + s * 32 + quad * 8;
      union { unsigned short u[8]; short8 v; } t;
#pragma unroll
      for (int k = 0; k < 8; ++k) t.u[k] = f2bf(ap[k]);
      a[s] = t.v;
    } else {
      a[s] = *(const short8*)((const unsigned short*)Av + (size_t)nodeA * 128 + s * 32 + quad * 8);
    }
  }

  f32x4 accl[8], accr[8];
#pragma unroll
  for (int jt = 0; jt < 8; ++jt) {
    accl[jt] = (f32x4){0.f, 0.f, 0.f, 0.f};
    accr[jt] = (f32x4){0.f, 0.f, 0.f, 0.f};
  }

#pragma unroll
  for (int jt = 0; jt < 8; ++jt) {
#pragma unroll
    for (int s = 0; s < 4; ++s) {
      int c = (s * 8 + jt) * 4 + quad;
      short8 bl = *(const short8*)(wsh + (c * 16 + nn) * 8);
      short8 br = *(const short8*)(wsh + 16384 + (c * 16 + nn) * 8);
      accl[jt] = __builtin_amdgcn_mfma_f32_16x16x32_bf16(a[s], bl, accl[jt], 0, 0, 0);
      accr[jt] = __builtin_amdgcn_mfma_f32_16x16x32_bf16(a[s], br, accr[jt], 0, 0, 0);
    }
  }

#pragma unroll
  for (int jt = 0; jt < 8; ++jt) {
#pragma unroll
    for (int r = 0; r < 4; ++r) {
      int ro = rowbase + quad * 4 + r;
      if (ro < n) {
        int col = jt * 16 + nn;
        Y[(size_t)ro * 128 + col] = accr[jt][r];
        Z[(size_t)ro * 128 + col] = f2bf(accl[jt][r]);
      }
    }
  }
}

// ---------------- fused mean-aggregate + bias + self + (relu) ----------------
// one wave per 2 consecutive nodes; 4 edge-slots x 16 column-lanes; up to 8
// 16B gathers in flight per lane. ALL __shfl executed with full wave exec
// (divergent-source bpermute returns garbage on CDNA — R5/R6 bug).
// Ybuf/outp may alias (layer 2) — not restrict-qualified.
template <int RELU, int OUTBF>
__global__ __launch_bounds__(256, 4) void agg_fuse2(
    const unsigned short* __restrict__ Z, const float* Ybuf,
    const float* __restrict__ bias, const float* __restrict__ inv,
    const int* __restrict__ offs, const int* __restrict__ cnt,
    const int* __restrict__ csr, void* outp, int n) {
  int pr = (int)((blockIdx.x * 256 + threadIdx.x) >> 6);
  int n0 = pr * 2;
  if (n0 >= n) return;
  const int n1 = n0 + 1;
  const bool has1 = (n1 < n);
  const int lane = threadIdx.x & 63;
  const int g = lane >> 4;      // edge slot 0..3
  const int l = lane & 15;      // column chunk: columns l*8 .. l*8+7
  const int deg0 = cnt[n0];
  const int deg1 = has1 ? cnt[n1] : 0;
  const int start = offs[n0];
  const int T = deg0 + deg1;    // CSR rows adjacent -> combined segment
  float acc0[8] = {0.f, 0.f, 0.f, 0.f, 0.f, 0.f, 0.f, 0.f};
  float acc1[8] = {0.f, 0.f, 0.f, 0.f, 0.f, 0.f, 0.f, 0.f};

  if (T <= 64) {
    int idx = (lane < T) ? csr[start + lane] : 0;
    int jmax = (T + 3) >> 2;    // wave-uniform
#pragma unroll 4
    for (int j = 0; j < jmax; ++j) {
      int e = j * 4 + g;        // <= 63
      int nbv = __shfl(idx, e); // full-exec shfl
      if (e < T) {
        uint4 v = *(const uint4*)(Z + (size_t)nbv * 128 + l * 8);
        if (e < deg0) addv8(acc0, v);
        else addv8(acc1, v);
      }
    }
  } else {
    // rare generic path (T > 64 essentially never at mean degree 16)
    for (int node = 0; node < 2; ++node) {
      int dg = node ? deg1 : deg0;
      int st = node ? (start + deg0) : start;
      for (int base = 0; base < dg; base += 64) {
        int m = dg - base;
        if (m > 64) m = 64;
        int idx = (lane < m) ? csr[st + base + lane] : 0;
#pragma unroll 4
        for (int i = 0; i < m; i += 4) {
          int sl = i + g;
          int nbv = __shfl(idx, sl & 63);  // full-exec shfl
          if (sl < m) {
            uint4 v = *(const uint4*)(Z + (size_t)nbv * 128 + l * 8);
            if (node) addv8(acc1, v);
            else addv8(acc0, v);
          }
        }
      }
    }
  }

  // reduce the 4 edge-slots (lanes differing in bits 4..5)
#pragma unroll
  for (int j = 0; j < 8; ++j) {
    acc0[j] += __shfl_xor(acc0[j], 16);
    acc0[j] += __shfl_xor(acc0[j], 32);
    acc1[j] += __shfl_xor(acc1[j], 16);
    acc1[j] += __shfl_xor(acc1[j], 32);
  }

  const int c0 = l * 8 + g * 2;
  const float bv0 = bias[c0], bv1 = bias[c0 + 1];

  {
    float s = inv[n0];
    float2 yv = *(const float2*)(Ybuf + (size_t)n0 * 128 + c0);
    float o0 = fmaf(acc0[g * 2 + 0], s, bv0 + yv.x);
    float o1 = fmaf(acc0[g * 2 + 1], s, bv1 + yv.y);
    if (RELU) { o0 = fmaxf(o0, 0.f); o1 = fmaxf(o1, 0.f); }
    if (OUTBF) {
      unsigned pkt = (unsigned)f2bf(o0) | ((unsigned)f2bf(o1) << 16);
      *(unsigned*)((unsigned short*)outp + (size_t)n0 * 128 + c0) = pkt;
    } else {
      *(float2*)((float*)outp + (size_t)n0 * 128 + c0) = make_float2(o0, o1);
    }
  }
  if (has1) {
    float s = inv[n1];
    float2 yv = *(const float2*)(Ybuf + (size_t)n1 * 128 + c0);
    float o0 = fmaf(acc1[g * 2 + 0], s, bv0 + yv.x);
    float o1 = fmaf(acc1[g * 2 + 1], s, bv1 + yv.y);
    if (RELU) { o0 = fmaxf(o0, 0.f); o1 = fmaxf(o1, 0.f); }
    if (OUTBF) {
      unsigned pkt = (unsigned)f2bf(o0) | ((unsigned)f2bf(o1) << 16);
      *(unsigned*)((unsigned short*)outp + (size_t)n1 * 128 + c0) = pkt;
    } else {
      *(float2*)((float*)outp + (size_t)n1 * 128 + c0) = make_float2(o0, o1);
    }
  }
}

// ---------------- launch ----------------

extern "C" void kernel_launch(void* const* d_in, const int* in_sizes, int n_in,
                              void* d_out, int out_size, void* d_ws, size_t ws_size,
                              hipStream_t stream) {
  const float* x = (const float*)d_in[0];
  const int* ei = (const int*)d_in[1];
  const float* W1l = (const float*)d_in[2];
  const float* b1 = (const float*)d_in[3];
  const float* W1r = (const float*)d_in[4];
  const float* W2l = (const float*)d_in[5];
  const float* b2 = (const float*)d_in[6];
  const float* W2r = (const float*)d_in[7];
  float* out = (float*)d_out;

  const int N = in_sizes[0] / 128;
  const int E = in_sizes[1] / 2;
  const int nb = (N + 255) / 256;   // buckets of 256 nodes; must be <= NBMAX

  char* p = (char*)d_ws;
  auto alloc = [&](size_t bytes) {
    char* r = p;
    p += (bytes + 255) & ~(size_t)255;
    return r;
  };
  int* flag = (int*)alloc(256);
  int* cnt = (int*)alloc((size_t)N * 4);
  int* offs = (int*)alloc((size_t)N * 4);
  float* inv = (float*)alloc((size_t)N * 4);
  int* bsums = (int*)alloc(4096);
  int* bcur = (int*)alloc((size_t)NBMAX * 4);
  int* csr = (int*)alloc((size_t)E * 4);
  unsigned short* zb = (unsigned short*)alloc((size_t)N * 128 * 2);  // 25.6 MB
  unsigned short* hb = (unsigned short*)alloc((size_t)N * 128 * 2);  // 25.6 MB
  int2* stage = (int2*)hb;  // 12.8 MB alias — stage dead before agg1 writes hb

  hipMemsetAsync(cnt, 0, (size_t)N * 4, stream);

  const int TB = 256;
  detect_k<<<1, 256, 0, stream>>>(ei, E, flag);
  hist_k<<<(E + TB - 1) / TB, TB, 0, stream>>>(ei, cnt, E, flag);
  const int nb1 = (N + 255) / 256;
  scan1<<<nb1, 256, 0, stream>>>(cnt, offs, bsums, inv, N);
  scan23<<<nb1, 256, 0, stream>>>(offs, bsums, bcur, N);
  bucket_scatter<<<(E + 4095) / 4096, 256, 0, stream>>>(ei, E, flag, bcur, stage);
  bucket_fill<<<nb, 256, 0, stream>>>(stage, offs, csr, N, E);

  const int gb = (N + 63) / 64;
  const int pairs = (N + 1) / 2;
  const int ab2 = (pairs + 3) / 4;   // 4 waves (=4 pairs) per 256-thread block

  // layer 1: Y1 -> d_out (f32); Z1 -> zb (bf16); h (bf16, post-relu) -> hb
  dual_gemm<1><<<gb, 256, 0, stream>>>((const void*)x, W1l, W1r, zb, out, N);
  agg_fuse2<1, 1><<<ab2, 256, 0, stream>>>(zb, out, b1, inv, offs, cnt, csr, (void*)hb, N);
  // layer 2: A = hb (bf16); Y2 -> d_out; Z2 -> zb; final out in-place in d_out
  dual_gemm<0><<<gb, 256, 0, stream>>>((const void*)hb, W2l, W2r, zb, out, N);
  agg_fuse2<0, 0><<<ab2, 256, 0, stream>>>(zb, out, b2, inv, offs, cnt, csr, (void*)out, N);
}

// Round 8
// 339.853 us; speedup vs baseline: 1.6993x; 1.1879x over previous
//
#include <hip/hip_runtime.h>

typedef __attribute__((ext_vector_type(8))) short short8;
typedef __attribute__((ext_vector_type(4))) float f32x4;

#define NBMAX 512
#define CAP 8192   // per-bucket stage capacity; mean load 4096, sigma ~64

__device__ inline unsigned short f2bf(float f) {
  union { float f; unsigned u; } v; v.f = f;
  unsigned r = v.u + 0x7fffu + ((v.u >> 16) & 1u);
  return (unsigned short)(r >> 16);
}
__device__ inline float bf2f(unsigned short b) {
  union { unsigned u; float f; } v; v.u = ((unsigned)b) << 16;
  return v.f;
}

__device__ inline void addv8(float (&a)[8], uint4 v) {
  a[0] += bf2f((unsigned short)(v.x & 0xffffu));
  a[1] += bf2f((unsigned short)(v.x >> 16));
  a[2] += bf2f((unsigned short)(v.y & 0xffffu));
  a[3] += bf2f((unsigned short)(v.y >> 16));
  a[4] += bf2f((unsigned short)(v.z & 0xffffu));
  a[5] += bf2f((unsigned short)(v.z >> 16));
  a[6] += bf2f((unsigned short)(v.w & 0xffffu));
  a[7] += bf2f((unsigned short)(v.w >> 16));
}

__device__ inline int load_src(const int* ei, int E, int e, int f64) {
  return f64 ? ei[2 * e] : ei[e];
}
__device__ inline int load_dst(const int* ei, int E, int e, int f64) {
  return f64 ? ei[2 * (E + e)] : ei[E + e];
}

// ---------------- CSR build, phase A ----------------
// bucket = dst>>8. LDS histogram -> bulk reserve on global btot -> clustered
// append (src,dst) into the bucket's fixed-capacity stage region.
// Edge dtype detected per-block: in int64 layout ei[2e+1] is a zero high word;
// in int32 layout it's a random node id (256 of them never all zero).
__global__ __launch_bounds__(256) void scatter2(
    const int* __restrict__ ei, int E,
    int* __restrict__ btot, int2* __restrict__ stage) {
  __shared__ int lcnt[NBMAX];
  __shared__ int lbase[NBMAX];
  __shared__ int sflag;
  const int t = threadIdx.x;
  if (t == 0) sflag = 0;
  for (int i = t; i < NBMAX; i += 256) lcnt[i] = 0;
  __syncthreads();
  const int e0 = blockIdx.x * 4096;
  {
    int e = e0 + t;
    int v = (e < E) ? ei[2 * e + 1] : 0;   // in-bounds under both layouts
    if (v) atomicOr(&sflag, 1);
  }
  __syncthreads();
  const int f64 = (sflag == 0) ? 1 : 0;

  int srcs[16], bks[16];
  int dsts[16];
#pragma unroll
  for (int i = 0; i < 16; ++i) {
    int e = e0 + i * 256 + t;
    if (e < E) {
      srcs[i] = load_src(ei, E, e, f64);
      int d = load_dst(ei, E, e, f64);
      dsts[i] = d;
      bks[i] = d >> 8;
      atomicAdd(&lcnt[d >> 8], 1);
    } else {
      bks[i] = -1;
    }
  }
  __syncthreads();
  for (int i = t; i < NBMAX; i += 256) {
    int c = lcnt[i];
    lbase[i] = c ? atomicAdd(&btot[i], c) : 0;
  }
  __syncthreads();
  for (int i = t; i < NBMAX; i += 256) lcnt[i] = 0;
  __syncthreads();
#pragma unroll
  for (int i = 0; i < 16; ++i) {
    int b = bks[i];
    if (b >= 0) {
      int r = atomicAdd(&lcnt[b], 1);
      stage[(size_t)b * CAP + lbase[b] + r] = make_int2(srcs[i], dsts[i]);
    }
  }
}

// ---------------- CSR build, phase B ----------------
// one WG per bucket: cross-bucket prefix from btot, LDS 256-node histogram +
// scan -> offs/cnt/inv, then csr fill with LDS cursors (writes stay in a
// contiguous ~16KB window).
__global__ __launch_bounds__(256) void bucket_fill2(
    const int2* __restrict__ stage, const int* __restrict__ btot,
    int* __restrict__ offs, int* __restrict__ cnt, float* __restrict__ inv,
    int* __restrict__ csr, int N) {
  __shared__ int lhist[256];
  __shared__ int lscan[256];
  __shared__ int lcur[256];
  __shared__ int red[256];
  const int b = blockIdx.x;
  const int t = threadIdx.x;
  int sum = 0;
  for (int j = t; j < b; j += 256) sum += btot[j];
  red[t] = sum;
  lhist[t] = 0;
  __syncthreads();
  for (int d = 128; d; d >>= 1) {
    if (t < d) red[t] += red[t + d];
    __syncthreads();
  }
  const int base = red[0];
  const int count = btot[b];
  const int2* sp = stage + (size_t)b * CAP;
  for (int i = t; i < count; i += 256)
    atomicAdd(&lhist[sp[i].y & 255], 1);
  __syncthreads();
  int v = lhist[t];
  lscan[t] = v;
  __syncthreads();
  for (int d = 1; d < 256; d <<= 1) {
    int tv = (t >= d) ? lscan[t - d] : 0;
    __syncthreads();
    lscan[t] += tv;
    __syncthreads();
  }
  const int excl = lscan[t] - v;
  const int node = b * 256 + t;
  if (node < N) {
    offs[node] = base + excl;
    cnt[node] = v;
    inv[node] = 1.0f / (float)((v > 1) ? v : 1);
  }
  lcur[t] = base + excl;
  __syncthreads();
  for (int i = t; i < count; i += 256) {
    int2 sd = sp[i];
    int p = atomicAdd(&lcur[sd.y & 255], 1);
    csr[p] = sd.x;
  }
}

// ---------------- dual GEMM: Z = A@Wl^T (bf16), Y = A@Wr^T (f32) ----------------
template <int AF32>
__global__ __launch_bounds__(256) void dual_gemm(
    const void* __restrict__ Av,
    const float* __restrict__ Wl, const float* __restrict__ Wr,
    unsigned short* __restrict__ Z, float* __restrict__ Y, int n) {
  __shared__ unsigned short wsh[2 * 16384];  // 64 KiB
  const int tid = threadIdx.x;

  for (int mi = 0; mi < 2; ++mi) {
    const float* W = mi ? Wr : Wl;
#pragma unroll
    for (int it = 0; it < 8; ++it) {
      int id = it * 256 + tid;
      int j = id >> 4;
      int kc = id & 15;
      int s = kc >> 2, q = kc & 3;
      int jt = j >> 4, nn2 = j & 15;
      int c = (s * 8 + jt) * 4 + q;
      const float* src = W + j * 128 + kc * 8;
      union { unsigned short u[8]; uint4 v; } t;
#pragma unroll
      for (int k = 0; k < 8; ++k) t.u[k] = f2bf(src[k]);
      *(uint4*)(wsh + mi * 16384 + (c * 16 + nn2) * 8) = t.v;
    }
  }
  __syncthreads();

  const int lane = tid & 63;
  const int wave = tid >> 6;
  const int nn = lane & 15;
  const int quad = lane >> 4;
  const int rowbase = blockIdx.x * 64 + wave * 16;

  int nodeA = rowbase + nn;
  if (nodeA > n - 1) nodeA = n - 1;

  short8 a[4];
#pragma unroll
  for (int s = 0; s < 4; ++s) {
    if (AF32) {
      const float* ap = (const float*)Av + (size_t)nodeA * 128 + s * 32 + quad * 8;
      union { unsigned short u[8]; short8 v; } t;
#pragma unroll
      for (int k = 0; k < 8; ++k) t.u[k] = f2bf(ap[k]);
      a[s] = t.v;
    } else {
      a[s] = *(const short8*)((const unsigned short*)Av + (size_t)nodeA * 128 + s * 32 + quad * 8);
    }
  }

  f32x4 accl[8], accr[8];
#pragma unroll
  for (int jt = 0; jt < 8; ++jt) {
    accl[jt] = (f32x4){0.f, 0.f, 0.f, 0.f};
    accr[jt] = (f32x4){0.f, 0.f, 0.f, 0.f};
  }

#pragma unroll
  for (int jt = 0; jt < 8; ++jt) {
#pragma unroll
    for (int s = 0; s < 4; ++s) {
      int c = (s * 8 + jt) * 4 + quad;
      short8 bl = *(const short8*)(wsh + (c * 16 + nn) * 8);
      short8 br = *(const short8*)(wsh + 16384 + (c * 16 + nn) * 8);
      accl[jt] = __builtin_amdgcn_mfma_f32_16x16x32_bf16(a[s], bl, accl[jt], 0, 0, 0);
      accr[jt] = __builtin_amdgcn_mfma_f32_16x16x32_bf16(a[s], br, accr[jt], 0, 0, 0);
    }
  }

#pragma unroll
  for (int jt = 0; jt < 8; ++jt) {
#pragma unroll
    for (int r = 0; r < 4; ++r) {
      int ro = rowbase + quad * 4 + r;
      if (ro < n) {
        int col = jt * 16 + nn;
        Y[(size_t)ro * 128 + col] = accr[jt][r];
        Z[(size_t)ro * 128 + col] = f2bf(accl[jt][r]);
      }
    }
  }
}

// ---------------- fused mean-aggregate + bias + self + (relu) ----------------
// one wave per 2 consecutive nodes; 4 edge-slots x 16 column-lanes; all __shfl
// at full wave exec (divergent-source shfl returns garbage on CDNA).
// Ybuf/outp may alias (layer 2) — not restrict-qualified.
template <int RELU, int OUTBF>
__global__ __launch_bounds__(256, 4) void agg_fuse2(
    const unsigned short* __restrict__ Z, const float* Ybuf,
    const float* __restrict__ bias, const float* __restrict__ inv,
    const int* __restrict__ offs, const int* __restrict__ cnt,
    const int* __restrict__ csr, void* outp, int n) {
  int pr = (int)((blockIdx.x * 256 + threadIdx.x) >> 6);
  int n0 = pr * 2;
  if (n0 >= n) return;
  const int n1 = n0 + 1;
  const bool has1 = (n1 < n);
  const int lane = threadIdx.x & 63;
  const int g = lane >> 4;      // edge slot 0..3
  const int l = lane & 15;      // column chunk: columns l*8 .. l*8+7
  const int deg0 = cnt[n0];
  const int deg1 = has1 ? cnt[n1] : 0;
  const int start = offs[n0];
  const int T = deg0 + deg1;    // CSR rows adjacent -> combined segment
  float acc0[8] = {0.f, 0.f, 0.f, 0.f, 0.f, 0.f, 0.f, 0.f};
  float acc1[8] = {0.f, 0.f, 0.f, 0.f, 0.f, 0.f, 0.f, 0.f};

  if (T <= 64) {
    int idx = (lane < T) ? csr[start + lane] : 0;
    int jmax = (T + 3) >> 2;    // wave-uniform
#pragma unroll 8
    for (int j = 0; j < jmax; ++j) {
      int e = j * 4 + g;        // <= 63
      int nbv = __shfl(idx, e); // full-exec shfl
      if (e < T) {
        uint4 v = *(const uint4*)(Z + (size_t)nbv * 128 + l * 8);
        if (e < deg0) addv8(acc0, v);
        else addv8(acc1, v);
      }
    }
  } else {
    // rare generic path (T > 64 essentially never at mean degree 16)
    for (int node = 0; node < 2; ++node) {
      int dg = node ? deg1 : deg0;
      int st = node ? (start + deg0) : start;
      for (int base = 0; base < dg; base += 64) {
        int m = dg - base;
        if (m > 64) m = 64;
        int idx = (lane < m) ? csr[st + base + lane] : 0;
#pragma unroll 4
        for (int i = 0; i < m; i += 4) {
          int sl = i + g;
          int nbv = __shfl(idx, sl & 63);  // full-exec shfl
          if (sl < m) {
            uint4 v = *(const uint4*)(Z + (size_t)nbv * 128 + l * 8);
            if (node) addv8(acc1, v);
            else addv8(acc0, v);
          }
        }
      }
    }
  }

  // reduce the 4 edge-slots (lanes differing in bits 4..5)
#pragma unroll
  for (int j = 0; j < 8; ++j) {
    acc0[j] += __shfl_xor(acc0[j], 16);
    acc0[j] += __shfl_xor(acc0[j], 32);
    acc1[j] += __shfl_xor(acc1[j], 16);
    acc1[j] += __shfl_xor(acc1[j], 32);
  }

  const int c0 = l * 8 + g * 2;
  const float bv0 = bias[c0], bv1 = bias[c0 + 1];

  {
    float s = inv[n0];
    float2 yv = *(const float2*)(Ybuf + (size_t)n0 * 128 + c0);
    float o0 = fmaf(acc0[g * 2 + 0], s, bv0 + yv.x);
    float o1 = fmaf(acc0[g * 2 + 1], s, bv1 + yv.y);
    if (RELU) { o0 = fmaxf(o0, 0.f); o1 = fmaxf(o1, 0.f); }
    if (OUTBF) {
      unsigned pkt = (unsigned)f2bf(o0) | ((unsigned)f2bf(o1) << 16);
      *(unsigned*)((unsigned short*)outp + (size_t)n0 * 128 + c0) = pkt;
    } else {
      *(float2*)((float*)outp + (size_t)n0 * 128 + c0) = make_float2(o0, o1);
    }
  }
  if (has1) {
    float s = inv[n1];
    float2 yv = *(const float2*)(Ybuf + (size_t)n1 * 128 + c0);
    float o0 = fmaf(acc1[g * 2 + 0], s, bv0 + yv.x);
    float o1 = fmaf(acc1[g * 2 + 1], s, bv1 + yv.y);
    if (RELU) { o0 = fmaxf(o0, 0.f); o1 = fmaxf(o1, 0.f); }
    if (OUTBF) {
      unsigned pkt = (unsigned)f2bf(o0) | ((unsigned)f2bf(o1) << 16);
      *(unsigned*)((unsigned short*)outp + (size_t)n1 * 128 + c0) = pkt;
    } else {
      *(float2*)((float*)outp + (size_t)n1 * 128 + c0) = make_float2(o0, o1);
    }
  }
}

// ---------------- launch ----------------

extern "C" void kernel_launch(void* const* d_in, const int* in_sizes, int n_in,
                              void* d_out, int out_size, void* d_ws, size_t ws_size,
                              hipStream_t stream) {
  const float* x = (const float*)d_in[0];
  const int* ei = (const int*)d_in[1];
  const float* W1l = (const float*)d_in[2];
  const float* b1 = (const float*)d_in[3];
  const float* W1r = (const float*)d_in[4];
  const float* W2l = (const float*)d_in[5];
  const float* b2 = (const float*)d_in[6];
  const float* W2r = (const float*)d_in[7];
  float* out = (float*)d_out;

  const int N = in_sizes[0] / 128;
  const int E = in_sizes[1] / 2;
  const int nb = (N + 255) / 256;   // buckets of 256 nodes; must be <= NBMAX

  char* p = (char*)d_ws;
  auto alloc = [&](size_t bytes) {
    char* r = p;
    p += (bytes + 255) & ~(size_t)255;
    return r;
  };
  int* btot = (int*)alloc((size_t)NBMAX * 4);
  int* cnt = (int*)alloc((size_t)N * 4);
  int* offs = (int*)alloc((size_t)N * 4);
  float* inv = (float*)alloc((size_t)N * 4);
  int* csr = (int*)alloc((size_t)E * 4);
  unsigned short* zb = (unsigned short*)alloc((size_t)N * 128 * 2);   // 25.6 MB
  size_t stage_bytes = (size_t)nb * CAP * 8;
  size_t hb_bytes = (size_t)N * 128 * 2;
  char* shared_region = alloc(stage_bytes > hb_bytes ? stage_bytes : hb_bytes);
  unsigned short* hb = (unsigned short*)shared_region;  // h (bf16) after CSR done
  int2* stage = (int2*)shared_region;                   // staging during CSR build

  hipMemsetAsync(btot, 0, (size_t)nb * 4, stream);

  scatter2<<<(E + 4095) / 4096, 256, 0, stream>>>(ei, E, btot, stage);
  bucket_fill2<<<nb, 256, 0, stream>>>(stage, btot, offs, cnt, inv, csr, N);

  const int gb = (N + 63) / 64;
  const int pairs = (N + 1) / 2;
  const int ab2 = (pairs + 3) / 4;   // 4 waves (=4 pairs) per 256-thread block

  // layer 1: Y1 -> d_out (f32); Z1 -> zb (bf16); h (bf16, post-relu) -> hb
  dual_gemm<1><<<gb, 256, 0, stream>>>((const void*)x, W1l, W1r, zb, out, N);
  agg_fuse2<1, 1><<<ab2, 256, 0, stream>>>(zb, out, b1, inv, offs, cnt, csr, (void*)hb, N);
  // layer 2: A = hb (bf16); Y2 -> d_out; Z2 -> zb; final out in-place in d_out
  dual_gemm<0><<<gb, 256, 0, stream>>>((const void*)hb, W2l, W2r, zb, out, N);
  agg_fuse2<0, 0><<<ab2, 256, 0, stream>>>(zb, out, b2, inv, offs, cnt, csr, (void*)out, N);
}